// Round 1
// baseline (91.086 us; speedup 1.0000x reference)
//
#include <hip/hip_runtime.h>

// BlockLinear: out[h*64+i][b] = sum_j W[h][i][j] * inp[h*64+j][b]
// H=16 blocks of 64x64 fp32, B=32768 columns. Memory-bound (AI = 16 FLOP/B).

constexpr int H   = 16;
constexpr int D   = 64;
constexpr int B   = 32768;
constexpr int PAD = 68;  // LDS row stride in floats: 68*4=272 B, 16B-aligned rows

__global__ __launch_bounds__(256, 4)
void block_linear_kernel(const float* __restrict__ W,
                         const float* __restrict__ inp,
                         float* __restrict__ out)
{
    __shared__ float Wt[D * PAD];  // Wt[j*PAD + i] = W[h][i][j] (transposed)

    const int tid = threadIdx.x;
    const int h   = blockIdx.y;
    const float* Wh = W + h * D * D;

    // Stage + transpose W[h] into LDS. Coalesced global reads; LDS write
    // conflicts are one-time (16 writes/thread) and negligible.
    #pragma unroll
    for (int k = 0; k < (D * D) / 256; ++k) {
        int idx = k * 256 + tid;
        int i = idx >> 6;   // row of W (output row)
        int j = idx & 63;   // col of W (input row)
        Wt[j * PAD + i] = Wh[idx];
    }
    __syncthreads();

    const long long b = (long long)blockIdx.x * 256 + tid;
    const float* xptr = inp + (long long)h * D * B + b;
    float*       optr = out + (long long)h * D * B + b;

    float acc[D];
    #pragma unroll
    for (int i = 0; i < D; ++i) acc[i] = 0.0f;

    // Stream x down the column; each LDS b128 read feeds 4 FMAs.
    #pragma unroll 4
    for (int j = 0; j < D; ++j) {
        float xj = xptr[(long long)j * B];
        const float4* wrow = (const float4*)&Wt[j * PAD];
        #pragma unroll
        for (int q = 0; q < D / 4; ++q) {
            float4 w = wrow[q];  // broadcast: all lanes same address
            acc[4 * q + 0] = fmaf(w.x, xj, acc[4 * q + 0]);
            acc[4 * q + 1] = fmaf(w.y, xj, acc[4 * q + 1]);
            acc[4 * q + 2] = fmaf(w.z, xj, acc[4 * q + 2]);
            acc[4 * q + 3] = fmaf(w.w, xj, acc[4 * q + 3]);
        }
    }

    #pragma unroll
    for (int i = 0; i < D; ++i)
        optr[(long long)i * B] = acc[i];
}

extern "C" void kernel_launch(void* const* d_in, const int* in_sizes, int n_in,
                              void* d_out, int out_size, void* d_ws, size_t ws_size,
                              hipStream_t stream) {
    const float* W   = (const float*)d_in[0];
    const float* inp = (const float*)d_in[1];
    float*       out = (float*)d_out;

    dim3 grid(B / 256, H);   // 128 x 16 = 2048 workgroups
    block_linear_kernel<<<grid, dim3(256), 0, stream>>>(W, inp, out);
}

// Round 2
// 86.970 us; speedup vs baseline: 1.0473x; 1.0473x over previous
//
#include <hip/hip_runtime.h>

// BlockLinear: out[h*64+i][b] = sum_j W[h][i][j] * inp[h*64+j][b]
// H=16 blocks of 64x64 fp32, B=32768 columns.
// Round 2: LDS-BW was the limiter (8.6 GB LDS reads @69 TB/s = 124 us = measured).
// Fix: 4 batch-cols per thread + 16-row i-tile per wave -> 1 B LDS per FMA.

constexpr int H   = 16;
constexpr int D   = 64;
constexpr int B   = 32768;
constexpr int PAD = 68;  // LDS row stride in floats; 68*4=272 B keeps 16B alignment

__global__ __launch_bounds__(256, 4)
void block_linear_kernel(const float* __restrict__ W,
                         const float* __restrict__ inp,
                         float* __restrict__ out)
{
    __shared__ float Wt[D * PAD];  // Wt[j*PAD + i] = W[h][i][j] (transposed)

    const int tid  = threadIdx.x;
    const int lane = tid & 63;
    const int wv   = tid >> 6;          // wave id 0..3 -> i-tile [wv*16, wv*16+16)
    const int h    = blockIdx.y;
    const float* Wh = W + h * D * D;

    // Stage + transpose W[h] into LDS (one-time; coalesced global reads).
    #pragma unroll
    for (int k = 0; k < (D * D) / 256; ++k) {
        int idx = k * 256 + tid;
        int i = idx >> 6;
        int j = idx & 63;
        Wt[j * PAD + i] = Wh[idx];
    }
    __syncthreads();

    // Each wave covers the same 256 columns, different 16 output rows.
    const long long col  = (long long)blockIdx.x * 256 + lane * 4;
    const float* xptr = inp + (long long)h * D * B + col;
    float*       optr = out + (long long)h * D * B + (long long)(wv * 16) * B + col;

    float acc[16][4];
    #pragma unroll
    for (int i = 0; i < 16; ++i)
        #pragma unroll
        for (int c = 0; c < 4; ++c) acc[i][c] = 0.0f;

    #pragma unroll 4
    for (int j = 0; j < D; ++j) {
        float4 x = *(const float4*)(xptr + (long long)j * B);       // 16 B/lane coalesced
        const float4* wr = (const float4*)&Wt[j * PAD + wv * 16];   // wave-broadcast
        #pragma unroll
        for (int q = 0; q < 4; ++q) {
            float4 w = wr[q];  // 1 ds_read_b128 feeds 16 FMAs
            acc[q * 4 + 0][0] = fmaf(w.x, x.x, acc[q * 4 + 0][0]);
            acc[q * 4 + 0][1] = fmaf(w.x, x.y, acc[q * 4 + 0][1]);
            acc[q * 4 + 0][2] = fmaf(w.x, x.z, acc[q * 4 + 0][2]);
            acc[q * 4 + 0][3] = fmaf(w.x, x.w, acc[q * 4 + 0][3]);
            acc[q * 4 + 1][0] = fmaf(w.y, x.x, acc[q * 4 + 1][0]);
            acc[q * 4 + 1][1] = fmaf(w.y, x.y, acc[q * 4 + 1][1]);
            acc[q * 4 + 1][2] = fmaf(w.y, x.z, acc[q * 4 + 1][2]);
            acc[q * 4 + 1][3] = fmaf(w.y, x.w, acc[q * 4 + 1][3]);
            acc[q * 4 + 2][0] = fmaf(w.z, x.x, acc[q * 4 + 2][0]);
            acc[q * 4 + 2][1] = fmaf(w.z, x.y, acc[q * 4 + 2][1]);
            acc[q * 4 + 2][2] = fmaf(w.z, x.z, acc[q * 4 + 2][2]);
            acc[q * 4 + 2][3] = fmaf(w.z, x.w, acc[q * 4 + 2][3]);
            acc[q * 4 + 3][0] = fmaf(w.w, x.x, acc[q * 4 + 3][0]);
            acc[q * 4 + 3][1] = fmaf(w.w, x.y, acc[q * 4 + 3][1]);
            acc[q * 4 + 3][2] = fmaf(w.w, x.z, acc[q * 4 + 3][2]);
            acc[q * 4 + 3][3] = fmaf(w.w, x.w, acc[q * 4 + 3][3]);
        }
    }

    #pragma unroll
    for (int i = 0; i < 16; ++i) {
        float4 v = { acc[i][0], acc[i][1], acc[i][2], acc[i][3] };
        *(float4*)(optr + (long long)i * B) = v;                    // 16 B/lane coalesced
    }
}

extern "C" void kernel_launch(void* const* d_in, const int* in_sizes, int n_in,
                              void* d_out, int out_size, void* d_ws, size_t ws_size,
                              hipStream_t stream) {
    const float* W   = (const float*)d_in[0];
    const float* inp = (const float*)d_in[1];
    float*       out = (float*)d_out;

    dim3 grid(B / 256, H);   // each block: 256 columns x all 64 rows of one h
    block_linear_kernel<<<grid, dim3(256), 0, stream>>>(W, inp, out);
}

// Round 3
// 69.055 us; speedup vs baseline: 1.3190x; 1.2594x over previous
//
#include <hip/hip_runtime.h>

// BlockLinear: out[h*64+i][b] = sum_j W[h][i][j] * inp[h*64+j][b]
// H=16 blocks of 64x64 fp32, B=32768 columns.
// Round 3: W is wave-uniform -> move it to SGPRs (s_load via uniform address),
// delete LDS entirely. 16 rows x 8 cols per thread; launch_bounds relaxed so
// the compiler has registers to hold 128 accumulators AND pipeline x-loads.

constexpr int H = 16;
constexpr int D = 64;
constexpr int B = 32768;

// Kernel 1: transpose W[h][i][j] -> Wt[h][j][i] so a 16-row slice at fixed j
// is contiguous (enables s_load_dwordx16 of the wave's W fragment).
__global__ void transpose_w(const float* __restrict__ W, float* __restrict__ Wt)
{
    const int h = blockIdx.x;
    const int t = threadIdx.x;
    #pragma unroll
    for (int k = 0; k < (D * D) / 256; ++k) {
        int idx = k * 256 + t;          // 0..4095
        int i = idx >> 6;
        int j = idx & 63;
        Wt[((long long)h * D + j) * D + i] = W[((long long)h * D + i) * D + j];
    }
}

__global__ __launch_bounds__(256, 1)
void block_linear_kernel(const float* __restrict__ Wt,
                         const float* __restrict__ inp,
                         float* __restrict__ out)
{
    const int tid  = threadIdx.x;
    const int lane = tid & 63;
    // Hoist wave id to SGPR so all W addresses are provably wave-uniform.
    const int wvu  = __builtin_amdgcn_readfirstlane(tid >> 6);
    const int h    = blockIdx.y;

    // Wave's W fragment base: rows [wvu*16, wvu*16+16) at column j, contiguous.
    const float* wbase = Wt + (long long)h * D * D + wvu * 16;

    const long long colbase = (long long)blockIdx.x * 512;
    const float* xptr = inp + (long long)h * D * B + colbase + lane * 4;
    float*       optr = out + ((long long)h * D + wvu * 16) * B + colbase + lane * 4;

    float acc[16][8];
    #pragma unroll
    for (int i = 0; i < 16; ++i)
        #pragma unroll
        for (int c = 0; c < 8; ++c) acc[i][c] = 0.0f;

    #pragma unroll 2
    for (int j = 0; j < D; ++j) {
        // Two fully-contiguous 1 KB wave loads (cols [0,256) and [256,512)).
        float4 x0 = *(const float4*)(xptr + (long long)j * B);
        float4 x1 = *(const float4*)(xptr + (long long)j * B + 256);
        const float* wr = wbase + j * D;   // uniform address -> s_load
        #pragma unroll
        for (int i = 0; i < 16; ++i) {
            float w = wr[i];               // SGPR operand to the FMAs
            acc[i][0] = fmaf(w, x0.x, acc[i][0]);
            acc[i][1] = fmaf(w, x0.y, acc[i][1]);
            acc[i][2] = fmaf(w, x0.z, acc[i][2]);
            acc[i][3] = fmaf(w, x0.w, acc[i][3]);
            acc[i][4] = fmaf(w, x1.x, acc[i][4]);
            acc[i][5] = fmaf(w, x1.y, acc[i][5]);
            acc[i][6] = fmaf(w, x1.z, acc[i][6]);
            acc[i][7] = fmaf(w, x1.w, acc[i][7]);
        }
    }

    #pragma unroll
    for (int i = 0; i < 16; ++i) {
        float4 a = { acc[i][0], acc[i][1], acc[i][2], acc[i][3] };
        float4 b = { acc[i][4], acc[i][5], acc[i][6], acc[i][7] };
        *(float4*)(optr + (long long)i * B)       = a;
        *(float4*)(optr + (long long)i * B + 256) = b;
    }
}

extern "C" void kernel_launch(void* const* d_in, const int* in_sizes, int n_in,
                              void* d_out, int out_size, void* d_ws, size_t ws_size,
                              hipStream_t stream) {
    const float* W   = (const float*)d_in[0];
    const float* inp = (const float*)d_in[1];
    float*       out = (float*)d_out;
    float*       Wt  = (float*)d_ws;   // 16*64*64*4 = 256 KB scratch

    transpose_w<<<dim3(H), dim3(256), 0, stream>>>(W, Wt);

    dim3 grid(B / 512, H);   // 64 x 16 = 1024 workgroups, 512 cols each
    block_linear_kernel<<<grid, dim3(256), 0, stream>>>(Wt, inp, out);
}

// Round 4
// 68.123 us; speedup vs baseline: 1.3371x; 1.0137x over previous
//
#include <hip/hip_runtime.h>

// BlockLinear: out[h*64+i][b] = sum_j W[h][i][j] * inp[h*64+j][b]
// H=16 blocks of 64x64 fp32, B=32768 columns.
// Round 4: latency/occupancy-bound. 16 rows x 4 cols per thread (64 acc ->
// fits registers, VGPR ~96 -> 5 waves/SIMD), 2048 blocks (8/CU), W via s_load
// (wave-uniform scalar path), explicit 2-deep x prefetch pipeline.

constexpr int H = 16;
constexpr int D = 64;
constexpr int B = 32768;

// Transpose W[h][i][j] -> Wt[h][j][i] so a wave's 16-row W slice at fixed j
// is contiguous (s_load_dwordx16-able).
__global__ void transpose_w(const float* __restrict__ W, float* __restrict__ Wt)
{
    const int h = blockIdx.x;
    const int t = threadIdx.x;
    #pragma unroll
    for (int k = 0; k < (D * D) / 256; ++k) {
        int idx = k * 256 + t;
        int i = idx >> 6;
        int j = idx & 63;
        Wt[((long long)h * D + j) * D + i] = W[((long long)h * D + i) * D + j];
    }
}

__global__ __launch_bounds__(256)
void block_linear_kernel(const float* __restrict__ Wt,
                         const float* __restrict__ inp,
                         float* __restrict__ out)
{
    const int tid  = threadIdx.x;
    const int lane = tid & 63;
    const int wvu  = __builtin_amdgcn_readfirstlane(tid >> 6);  // wave id 0..3
    const int h    = blockIdx.y;

    // Wave's W fragment: rows [wvu*16, wvu*16+16) at column j, contiguous.
    const float* wbase = Wt + (long long)h * D * D + wvu * 16;

    const long long col = (long long)blockIdx.x * 256 + lane * 4;
    const float* xptr = inp + (long long)h * D * B + col;
    float*       optr = out + ((long long)h * D + wvu * 16) * B + col;

    float acc[16][4];
    #pragma unroll
    for (int i = 0; i < 16; ++i)
        #pragma unroll
        for (int c = 0; c < 4; ++c) acc[i][c] = 0.0f;

    // 2-deep software pipeline on x: ~2 loads in flight per wave at all times.
    float4 x0 = *(const float4*)(xptr);                    // j = 0
    float4 x1 = *(const float4*)(xptr + (long long)B);     // j = 1

    for (int j = 0; j < D; ++j) {
        int jn = j + 2 < D ? j + 2 : D - 1;                // uniform clamp (no OOB)
        float4 xn = *(const float4*)(xptr + (long long)jn * B);
        const float* wr = wbase + j * D;                   // uniform -> s_load x16
        #pragma unroll
        for (int i = 0; i < 16; ++i) {
            float w = wr[i];                               // SGPR operand
            acc[i][0] = fmaf(w, x0.x, acc[i][0]);
            acc[i][1] = fmaf(w, x0.y, acc[i][1]);
            acc[i][2] = fmaf(w, x0.z, acc[i][2]);
            acc[i][3] = fmaf(w, x0.w, acc[i][3]);
        }
        x0 = x1;
        x1 = xn;
    }

    #pragma unroll
    for (int i = 0; i < 16; ++i) {
        float4 v = { acc[i][0], acc[i][1], acc[i][2], acc[i][3] };
        *(float4*)(optr + (long long)i * B) = v;
    }
}

extern "C" void kernel_launch(void* const* d_in, const int* in_sizes, int n_in,
                              void* d_out, int out_size, void* d_ws, size_t ws_size,
                              hipStream_t stream) {
    const float* W   = (const float*)d_in[0];
    const float* inp = (const float*)d_in[1];
    float*       out = (float*)d_out;
    float*       Wt  = (float*)d_ws;   // 16*64*64*4 = 256 KB scratch

    transpose_w<<<dim3(H), dim3(256), 0, stream>>>(W, Wt);

    dim3 grid(B / 256, H);   // 128 x 16 = 2048 workgroups, 256 cols each
    block_linear_kernel<<<grid, dim3(256), 0, stream>>>(Wt, inp, out);
}